// Round 1
// baseline (586.806 us; speedup 1.0000x reference)
//
#include <hip/hip_runtime.h>

// FM with per-field tables:
// x:   (16384, 20) int32   indices in [0, 100000)
// emb: (20, 100000, 64) float32  (512 MB)
// out: (16384,) float32 = sum(x,axis=1) + 0.5*(||sum_f v_f||^2 - sum_f ||v_f||^2)
//
// Two-phase restructure:
//  Kernel A (field-major gather): consecutive blocks share one field, so the
//    ~2048 co-resident blocks gather from ~2 field slices (~51 MB) at a time
//    instead of the whole 512 MB table. Writes V[row][field][:] to workspace
//    (84 MB, L3-resident random writes -> absorbed). No atomics.
//  Kernel B (row-major reduce): one wave per row streams its contiguous
//    20x256B V slice, computes interaction + linear term.

constexpr int BATCH = 16384;
constexpr int NUM_FIELDS = 20;
constexpr int NUM_FEATURES = 100000;
constexpr int LATENT = 64;

constexpr int ROWS_PER_WAVE_A = 4;                       // 4 gathers in flight/wave
constexpr int ROWS_PER_BLOCK_A = 4 * ROWS_PER_WAVE_A;    // 4 waves * 4 rows = 16
constexpr int CHUNKS_PER_FIELD = BATCH / ROWS_PER_BLOCK_A; // 1024

// ---------------- Kernel A: field-major gather ----------------
// grid = NUM_FIELDS * 1024; block = 256 threads (4 waves); wave = 4 rows.
__global__ __launch_bounds__(256)
void gather_kernel(const int* __restrict__ x,
                   const float* __restrict__ emb,
                   float* __restrict__ V) {
    const int wave = threadIdx.x >> 6;
    const int lane = threadIdx.x & 63;
    const int f     = blockIdx.x >> 10;          // CHUNKS_PER_FIELD == 1024
    const int chunk = blockIdx.x & 1023;
    const int r0 = chunk * ROWS_PER_BLOCK_A + wave * ROWS_PER_WAVE_A;

    const float* __restrict__ ef = emb + (size_t)f * NUM_FEATURES * LATENT;

#pragma unroll
    for (int g = 0; g < ROWS_PER_WAVE_A; ++g) {
        const int row = r0 + g;
        const int idx = x[row * NUM_FIELDS + f];         // wave-uniform load
        const float v = ef[idx * LATENT + lane];         // 256B coalesced gather
        V[((size_t)row * NUM_FIELDS + f) * LATENT + lane] = v;  // 256B coalesced store
    }
}

// ---------------- Kernel B: row-major reduce ----------------
// grid = BATCH/4; block = 256 threads (4 waves); one wave per row.
__global__ __launch_bounds__(256)
void reduce_kernel(const int* __restrict__ x,
                   const float* __restrict__ V,
                   float* __restrict__ out) {
    const int wave = threadIdx.x >> 6;
    const int lane = threadIdx.x & 63;
    const int row  = blockIdx.x * 4 + wave;

    const float* __restrict__ vr = V + (size_t)row * NUM_FIELDS * LATENT;

    float s = 0.0f, sq = 0.0f;
#pragma unroll
    for (int f = 0; f < NUM_FIELDS; ++f) {
        const float v = vr[f * LATENT + lane];           // contiguous 5KB/row stream
        s  += v;
        sq += v * v;
    }
    float t = 0.5f * (s * s - sq);

    // fold linear term into the same wave reduction (lanes 0..19 carry x)
    if (lane < NUM_FIELDS)
        t += (float)x[row * NUM_FIELDS + lane];

#pragma unroll
    for (int off = 32; off > 0; off >>= 1)
        t += __shfl_down(t, off, 64);

    if (lane == 0)
        out[row] = t;
}

// ---------------- Fallback: original fused kernel (if workspace too small) ----
__global__ __launch_bounds__(256)
void ffm_fused_kernel(const int* __restrict__ x,
                      const float* __restrict__ emb,
                      float* __restrict__ out) {
    const int wave_in_block = threadIdx.x >> 6;
    const int lane          = threadIdx.x & 63;
    const int row           = blockIdx.x * 4 + wave_in_block;
    if (row >= BATCH) return;

    const int* xr = x + row * NUM_FIELDS;

    float s = 0.0f, sq = 0.0f, xsum = 0.0f;
#pragma unroll
    for (int f = 0; f < NUM_FIELDS; ++f) {
        const int idx = xr[f];
        xsum += (float)idx;
        const int off = (f * NUM_FEATURES + idx) * LATENT + lane;
        const float v = emb[off];
        s  += v;
        sq += v * v;
    }
    float t = 0.5f * (s * s - sq);
#pragma unroll
    for (int off = 32; off > 0; off >>= 1)
        t += __shfl_down(t, off, 64);
    if (lane == 0)
        out[row] = xsum + t;
}

extern "C" void kernel_launch(void* const* d_in, const int* in_sizes, int n_in,
                              void* d_out, int out_size, void* d_ws, size_t ws_size,
                              hipStream_t stream) {
    const int*   x   = (const int*)d_in[0];
    // d_in[1] = field_indices (arange(20)) — unused, gather order is implicit
    const float* emb = (const float*)d_in[2];
    float*       out = (float*)d_out;

    const size_t v_bytes = (size_t)BATCH * NUM_FIELDS * LATENT * sizeof(float); // 84 MB

    if (d_ws != nullptr && ws_size >= v_bytes) {
        float* V = (float*)d_ws;
        gather_kernel<<<NUM_FIELDS * CHUNKS_PER_FIELD, 256, 0, stream>>>(x, emb, V);
        reduce_kernel<<<BATCH / 4, 256, 0, stream>>>(x, V, out);
    } else {
        const int grid = (BATCH + 3) / 4;
        ffm_fused_kernel<<<grid, 256, 0, stream>>>(x, emb, out);
    }
}